// Round 1
// 2806.056 us; speedup vs baseline: 1.0581x; 1.0581x over previous
//
#include <hip/hip_runtime.h>
#include <hip/hip_fp16.h>

#define E_ 8
#define B_ 4096
#define D_ 3072
#define H_ 1024
#define L_ 512
#define C_ 100

// d_out layout (floats): logits | recon | indices | min_err | relevance | mask
#define RECON_OFF  409600ull
#define IDX_OFF    101072896ull
#define MINERR_OFF 101076992ull
#define REL_OFF    101081088ull
#define MASK_OFF   101113856ull

typedef _Float16 half8 __attribute__((ext_vector_type(8)));
typedef float floatx4 __attribute__((ext_vector_type(4)));

#define AS1 __attribute__((address_space(1)))
#define AS3 __attribute__((address_space(3)))

__device__ __forceinline__ void gl16(const void* g, void* l) {
  __builtin_amdgcn_global_load_lds((const AS1 unsigned int*)g, (AS3 unsigned int*)l, 16, 0, 0);
}

enum { OM_HILO = 0, OM_HI = 1, OM_F32 = 2, OM_RECON = 3 };

// C = A @ W^T' + bias, per-expert batched. A: [e][M][K] fp16 hi(+lo unscaled),
// B: W^T [e][Npad][K] fp16 hi(+lo unscaled).
// SPLIT: lo is UNSCALED so all three products accumulate into ONE accumulator
// (saves 64 AGPRs -> 3 blocks/CU instead of 2).
// LDS chunk-XOR swizzle: LDS slot (row, chunk c) holds global chunk c ^ ((row>>1)&3).
// global_load_lds writes linearly, so the swizzle is applied on the per-lane GLOBAL
// source address (rule: both-sides-or-neither), and un-applied on the ds_read column.
// This turns the 8-way bank conflict of 64B-row tiles into a free 2-way.
template <int OM, bool RELU, bool SPLIT>
__launch_bounds__(256, SPLIT ? 3 : 4)
__global__ void gemm_k(const _Float16* __restrict__ Ah, const _Float16* __restrict__ Al,
                       const _Float16* __restrict__ Bh, const _Float16* __restrict__ Bl,
                       const float* __restrict__ bias, int biasN,
                       _Float16* __restrict__ Oh, _Float16* __restrict__ Ol,
                       float* __restrict__ Of, const float* __restrict__ Xf,
                       float* __restrict__ errOut,
                       int N, int K, int Npad, int Nstore, long aStrideE)
{
  const int M = B_;
  const int mBlocks = M >> 7;
  const int bx = blockIdx.x;
  const int mb = bx % mBlocks;
  const int nb = bx / mBlocks;
  const int e = blockIdx.y;
  const int m0 = mb << 7, n0 = nb << 7;
  const int tid = threadIdx.x;
  const int wave = tid >> 6, lane = tid & 63;
  const int wy = wave >> 1, wx = wave & 1;
  const int q = lane >> 4, t = lane & 15;

  __shared__ __align__(16) _Float16 sAh[128 * 32];
  __shared__ __align__(16) _Float16 sBh[128 * 32];
  __shared__ __align__(16) _Float16 sAl[SPLIT ? 128 * 32 : 8];
  __shared__ __align__(16) _Float16 sBl[SPLIT ? 128 * 32 : 8];
  __shared__ float ebuf[OM == OM_RECON ? 256 : 1];

  // staging: each wave stages 32 rows (2x16) of each tile; lane -> row lane/4,
  // 16B chunk (lane&3) XOR row-swizzle ((lane>>3)&3 == bits 1,2 of the LDS row)
  const int swzc = ((lane & 3) ^ ((lane >> 3) & 3)) * 8;
  const size_t aoff = (size_t)(m0 + wave * 32 + (lane >> 2)) * K + swzc;
  const size_t boff = (size_t)(n0 + wave * 32 + (lane >> 2)) * K + swzc;
  const _Float16* pAh = Ah + (size_t)e * aStrideE + aoff;
  const _Float16* pBh = Bh + (size_t)e * Npad * K + boff;
  const _Float16* pAl = SPLIT ? (Al + (size_t)e * aStrideE + aoff) : (const _Float16*)nullptr;
  const _Float16* pBl = SPLIT ? (Bl + (size_t)e * Npad * K + boff) : (const _Float16*)nullptr;
  _Float16* dAh = &sAh[(wave * 32) * 32];
  _Float16* dBh = &sBh[(wave * 32) * 32];
  _Float16* dAl = &sAl[SPLIT ? (wave * 32) * 32 : 0];
  _Float16* dBl = &sBl[SPLIT ? (wave * 32) * 32 : 0];

  // fragment-read column: un-apply the swizzle. Row = wy*64+i*16+t, so row bits
  // 1,2 == t bits 1,2 (i*16 and wy*64 only touch bits >=4).
  const int rcol = (q ^ ((t >> 1) & 3)) * 8;

  floatx4 acc[4][4] = {};

  for (int kt = 0; kt < K; kt += 32) {
    __syncthreads();
    gl16(pAh, dAh);
    gl16(pAh + (size_t)16 * K, dAh + 16 * 32);
    gl16(pBh, dBh);
    gl16(pBh + (size_t)16 * K, dBh + 16 * 32);
    if (SPLIT) {
      gl16(pAl, dAl);
      gl16(pAl + (size_t)16 * K, dAl + 16 * 32);
      gl16(pBl, dBl);
      gl16(pBl + (size_t)16 * K, dBl + 16 * 32);
    }
    pAh += 32; pBh += 32;
    if (SPLIT) { pAl += 32; pBl += 32; }
    __syncthreads();

    half8 a_h[4], b_h[4], a_l[4], b_l[4];
#pragma unroll
    for (int i = 0; i < 4; ++i) {
      a_h[i] = *(const half8*)&sAh[(wy * 64 + i * 16 + t) * 32 + rcol];
      b_h[i] = *(const half8*)&sBh[(wx * 64 + i * 16 + t) * 32 + rcol];
      if (SPLIT) {
        a_l[i] = *(const half8*)&sAl[(wy * 64 + i * 16 + t) * 32 + rcol];
        b_l[i] = *(const half8*)&sBl[(wx * 64 + i * 16 + t) * 32 + rcol];
      }
    }
#pragma unroll
    for (int i = 0; i < 4; ++i)
#pragma unroll
      for (int j = 0; j < 4; ++j) {
        acc[i][j] = __builtin_amdgcn_mfma_f32_16x16x32_f16(a_h[i], b_h[j], acc[i][j], 0, 0, 0);
        if (SPLIT) {
          acc[i][j] = __builtin_amdgcn_mfma_f32_16x16x32_f16(a_h[i], b_l[j], acc[i][j], 0, 0, 0);
          acc[i][j] = __builtin_amdgcn_mfma_f32_16x16x32_f16(a_l[i], b_h[j], acc[i][j], 0, 0, 0);
        }
      }
  }

  float esum[4][4];
#pragma unroll
  for (int i = 0; i < 4; ++i)
#pragma unroll
    for (int r = 0; r < 4; ++r) esum[i][r] = 0.0f;

#pragma unroll
  for (int j = 0; j < 4; ++j) {
    const int gcol = n0 + wx * 64 + j * 16 + t;
    float bj = 0.0f;
    if (OM == OM_F32) { if (gcol < biasN) bj = bias[e * biasN + gcol]; }
    else bj = bias[e * biasN + gcol];
#pragma unroll
    for (int i = 0; i < 4; ++i)
#pragma unroll
      for (int r = 0; r < 4; ++r) {
        float v = acc[i][j][r] + bj;
        if (RELU) v = fmaxf(v, 0.0f);
        const int grow = m0 + wy * 64 + i * 16 + q * 4 + r;
        if (OM == OM_HILO) {
          const size_t o = (size_t)e * M * N + (size_t)grow * N + gcol;
          _Float16 h = (_Float16)v;
          Oh[o] = h;
          Ol[o] = (_Float16)(v - (float)h);
        } else if (OM == OM_HI) {
          Oh[(size_t)e * M * N + (size_t)grow * N + gcol] = (_Float16)v;
        } else if (OM == OM_F32) {
          if (gcol < Nstore)
            Of[(size_t)e * M * Nstore + (size_t)grow * Nstore + gcol] = v;
        } else { // OM_RECON
          const size_t o = (size_t)e * M * N + (size_t)grow * N + gcol;
          Of[o] = v;
          esum[i][r] += fabsf(v - Xf[(size_t)grow * N + gcol]);
        }
      }
  }

  if (OM == OM_RECON) {
#pragma unroll
    for (int i = 0; i < 4; ++i)
#pragma unroll
      for (int r = 0; r < 4; ++r) {
        float s = esum[i][r];
        s += __shfl_xor(s, 1, 16);
        s += __shfl_xor(s, 2, 16);
        s += __shfl_xor(s, 4, 16);
        s += __shfl_xor(s, 8, 16);
        if (t == 0) ebuf[(wy * 64 + i * 16 + q * 4 + r) * 2 + wx] = s;
      }
    __syncthreads();
    if (tid < 128)
      atomicAdd(&errOut[(size_t)e * M + m0 + tid], ebuf[tid * 2] + ebuf[tid * 2 + 1]);
  }
}

// split x into hi/lo (lo UNSCALED)
__global__ void xsplit_k(const float* __restrict__ x, _Float16* __restrict__ xh,
                         _Float16* __restrict__ xl, int n)
{
  int i = blockIdx.x * 256 + threadIdx.x;
  if (i < n) {
    float v = x[i];
    _Float16 h = (_Float16)v;
    xh[i] = h;
    xl[i] = (_Float16)(v - (float)h);
  }
}

// W [e][K][N] fp32 -> W^T [e][Npad][K] fp16 hi (+ lo UNSCALED). Zero-fills n in [N, Npad).
__global__ void wprep_k(const float* __restrict__ W, _Float16* __restrict__ Th,
                        _Float16* __restrict__ Tl, int K, int N, int Npad)
{
  __shared__ float tile[32][33];
  const int e = blockIdx.z;
  const int k0 = blockIdx.x * 32, n0 = blockIdx.y * 32;
  const int tx = threadIdx.x, ty = threadIdx.y;
  const float* We = W + (size_t)e * K * N;
#pragma unroll
  for (int s = 0; s < 4; ++s) {
    int k = k0 + ty + s * 8, n = n0 + tx;
    tile[ty + s * 8][tx] = (n < N) ? We[(size_t)k * N + n] : 0.0f;
  }
  __syncthreads();
#pragma unroll
  for (int s = 0; s < 4; ++s) {
    int n = n0 + ty + s * 8, k = k0 + tx;
    float v = tile[tx][ty + s * 8];
    size_t o = ((size_t)e * Npad + n) * K + k;
    _Float16 h = (_Float16)v;
    Th[o] = h;
    if (Tl) Tl[o] = (_Float16)(v - (float)h);
  }
}

__global__ void finalize_k(const float* __restrict__ err, float* __restrict__ out,
                           int* __restrict__ idxbuf)
{
  int b = blockIdx.x * 256 + threadIdx.x;
  if (b >= B_) return;
  float ev[E_];
  float mn = 3.4e38f;
  int am = 0;
#pragma unroll
  for (int e = 0; e < E_; ++e) {
    float v = err[(size_t)e * B_ + b] * (1.0f / 3072.0f);
    ev[e] = v;
    if (v < mn) { mn = v; am = e; }
  }
  float den = 0.0f, w[E_];
#pragma unroll
  for (int e = 0; e < E_; ++e) { w[e] = expf((mn - ev[e]) * 0.5f); den += w[e]; }
  float inv = 1.0f / den;
  out[IDX_OFF + b] = (float)am;
  out[MINERR_OFF + b] = mn;
#pragma unroll
  for (int e = 0; e < E_; ++e) {
    out[REL_OFF + (size_t)e * B_ + b] = w[e] * inv;
    out[MASK_OFF + (size_t)e * B_ + b] = (e == am) ? 1.0f : 0.0f;
  }
  idxbuf[b] = am;
}

__global__ void gather_k(const float* __restrict__ expout, const int* __restrict__ idx,
                         float* __restrict__ out)
{
  int b = blockIdx.x;
  int c = threadIdx.x;
  if (c < C_) out[(size_t)b * C_ + c] = expout[((size_t)idx[b] * B_ + b) * C_ + c];
}

extern "C" void kernel_launch(void* const* d_in, const int* in_sizes, int n_in,
                              void* d_out, int out_size, void* d_ws, size_t ws_size,
                              hipStream_t stream)
{
  const float* x      = (const float*)d_in[0];
  const float* enc_w0 = (const float*)d_in[1];
  const float* enc_b0 = (const float*)d_in[2];
  const float* enc_w1 = (const float*)d_in[3];
  const float* enc_b1 = (const float*)d_in[4];
  const float* enc_w2 = (const float*)d_in[5];
  const float* enc_b2 = (const float*)d_in[6];
  const float* dec_w0 = (const float*)d_in[7];
  const float* dec_b0 = (const float*)d_in[8];
  const float* dec_w1 = (const float*)d_in[9];
  const float* dec_b1 = (const float*)d_in[10];
  const float* dec_w2 = (const float*)d_in[11];
  const float* dec_b2 = (const float*)d_in[12];
  const float* exp_w0 = (const float*)d_in[13];
  const float* exp_b0 = (const float*)d_in[14];
  const float* exp_w1 = (const float*)d_in[15];
  const float* exp_b1 = (const float*)d_in[16];
  const float* exp_w2 = (const float*)d_in[17];
  const float* exp_b2 = (const float*)d_in[18];

  // workspace layout (bytes)
  char* ws = (char*)d_ws;
  _Float16* xh     = (_Float16*)(ws + 0);          // 25165824
  _Float16* xl     = (_Float16*)(ws + 25165824);   // 25165824
  _Float16* WTh    = (_Float16*)(ws + 50331648);   // 50331648 (max layer)
  _Float16* WTl    = (_Float16*)(ws + 100663296);  // 50331648
  _Float16* lath   = (_Float16*)(ws + 150994944);  // 33554432
  _Float16* latl   = (_Float16*)(ws + 184549376);  // 33554432
  _Float16* g2h    = (_Float16*)(ws + 218103808);  // 67108864
  _Float16* g2l    = (_Float16*)(ws + 285212672);  // 67108864
  float*    expout = (float*)   (ws + 352321536);  // 13107200
  float*    errb   = (float*)   (ws + 365428736);  // 131072
  int*      idxb   = (int*)     (ws + 365559808);  // 16384

  float* out = (float*)d_out;
  float* recon = out + RECON_OFF;
  // activation double-buffers live in the (not yet written) recon region of d_out
  _Float16* bufAh = (_Float16*)recon;
  _Float16* bufAl = bufAh + (size_t)E_ * B_ * H_;
  _Float16* bufBh = bufAl + (size_t)E_ * B_ * H_;
  _Float16* bufBl = bufBh + (size_t)E_ * B_ * H_;

  hipMemsetAsync(errb, 0, (size_t)E_ * B_ * 4, stream);
  xsplit_k<<<(B_ * D_ + 255) / 256, 256, 0, stream>>>(x, xh, xl, B_ * D_);

  dim3 wb(32, 8);

  // L0: enc0  x[B,3072] @ W[3072,1024], relu -> h1 (bufA)
  wprep_k<<<dim3(96, 32, E_), wb, 0, stream>>>(enc_w0, WTh, WTl, 3072, 1024, 1024);
  gemm_k<OM_HILO, true, true><<<dim3(32 * 8, E_), 256, 0, stream>>>(
      xh, xl, WTh, WTl, enc_b0, 1024, bufAh, bufAl, nullptr, nullptr, nullptr,
      1024, 3072, 1024, 1024, 0L);
  // L1: enc1 -> h2 (bufB)
  wprep_k<<<dim3(32, 32, E_), wb, 0, stream>>>(enc_w1, WTh, WTl, 1024, 1024, 1024);
  gemm_k<OM_HILO, true, true><<<dim3(32 * 8, E_), 256, 0, stream>>>(
      bufAh, bufAl, WTh, WTl, enc_b1, 1024, bufBh, bufBl, nullptr, nullptr, nullptr,
      1024, 1024, 1024, 1024, (long)B_ * H_);
  // L2: enc2 (no relu) -> lat (ws)
  wprep_k<<<dim3(32, 16, E_), wb, 0, stream>>>(enc_w2, WTh, WTl, 1024, 512, 512);
  gemm_k<OM_HILO, false, true><<<dim3(32 * 4, E_), 256, 0, stream>>>(
      bufBh, bufBl, WTh, WTl, enc_b2, 512, lath, latl, nullptr, nullptr, nullptr,
      512, 1024, 512, 512, (long)B_ * H_);
  // Expert path (single precision fp16), before decoder so buffers can be reused
  // L6: exp0 -> e1 (bufA hi)
  wprep_k<<<dim3(16, 32, E_), wb, 0, stream>>>(exp_w0, WTh, nullptr, 512, 1024, 1024);
  gemm_k<OM_HI, true, false><<<dim3(32 * 8, E_), 256, 0, stream>>>(
      lath, nullptr, WTh, nullptr, exp_b0, 1024, bufAh, nullptr, nullptr, nullptr, nullptr,
      1024, 512, 1024, 1024, (long)B_ * L_);
  // L7: exp1 -> e2 (bufB hi)
  wprep_k<<<dim3(32, 32, E_), wb, 0, stream>>>(exp_w1, WTh, nullptr, 1024, 1024, 1024);
  gemm_k<OM_HI, true, false><<<dim3(32 * 8, E_), 256, 0, stream>>>(
      bufAh, nullptr, WTh, nullptr, exp_b1, 1024, bufBh, nullptr, nullptr, nullptr, nullptr,
      1024, 1024, 1024, 1024, (long)B_ * H_);
  // L8: exp2 -> expout [E,B,100] (ws); Npad=128 (zero-filled), store-guarded
  wprep_k<<<dim3(32, 4, E_), wb, 0, stream>>>(exp_w2, WTh, nullptr, 1024, 100, 128);
  gemm_k<OM_F32, false, false><<<dim3(32 * 1, E_), 256, 0, stream>>>(
      bufBh, nullptr, WTh, nullptr, exp_b2, 100, nullptr, nullptr, expout, nullptr, nullptr,
      128, 1024, 128, 100, (long)B_ * H_);
  // L3: dec0 -> g1 (bufA)
  wprep_k<<<dim3(16, 32, E_), wb, 0, stream>>>(dec_w0, WTh, WTl, 512, 1024, 1024);
  gemm_k<OM_HILO, true, true><<<dim3(32 * 8, E_), 256, 0, stream>>>(
      lath, latl, WTh, WTl, dec_b0, 1024, bufAh, bufAl, nullptr, nullptr, nullptr,
      1024, 512, 1024, 1024, (long)B_ * L_);
  // L4: dec1 -> g2 (ws; must NOT live in d_out because L5 overwrites it)
  wprep_k<<<dim3(32, 32, E_), wb, 0, stream>>>(dec_w1, WTh, WTl, 1024, 1024, 1024);
  gemm_k<OM_HILO, true, true><<<dim3(32 * 8, E_), 256, 0, stream>>>(
      bufAh, bufAl, WTh, WTl, dec_b1, 1024, g2h, g2l, nullptr, nullptr, nullptr,
      1024, 1024, 1024, 1024, (long)B_ * H_);
  // L5: dec2 (no relu) -> recon (d_out) + fused L1-err accumulation
  wprep_k<<<dim3(32, 96, E_), wb, 0, stream>>>(dec_w2, WTh, WTl, 1024, 3072, 3072);
  gemm_k<OM_RECON, false, true><<<dim3(32 * 24, E_), 256, 0, stream>>>(
      g2h, g2l, WTh, WTl, dec_b2, 3072, nullptr, nullptr, recon, x, errb,
      3072, 1024, 3072, 3072, (long)B_ * H_);

  finalize_k<<<(B_ + 255) / 256, 256, 0, stream>>>(errb, out, idxb);
  gather_k<<<B_, 128, 0, stream>>>(expout, idxb, out);
}